// Round 12
// baseline (106.174 us; speedup 1.0000x reference)
//
#include <hip/hip_runtime.h>

// Mo3ENet neighbor selection: B=256, PER=1024, NIN=256, NOUT=768, K=32, R=6
// Round 12: r11 skeleton (2 targets/wave, shared candidate reads, ballot
// compaction -> LDS slot rows -> coalesced epilogue, single-group pads)
// with an instruction diet: predicate-pair reuse for 'mine', +32-biased io
// counter, hoisted group index values, saddr-friendly epilogue stores.
// Outputs (concatenated float32):
//   [0) src_ii | [E) tgt | [2E) m_ii | [3E) dist_ii |
//   [4E) src_io | [5E) tgt | [6E) m_io | [7E) dist_io
//
// Per-wave, per-target LDS slot row (128 ints): [0..31] ii | [32..63] io |
// [64..127] dead (dump). Conditional writes select dump unless (mine && in
// range), so overflow never clobbers live slots.

constexpr int KK = 32;
constexpr unsigned EE = 2097152u;  // elements per output array

typedef float v2f __attribute__((ext_vector_type(2)));

__device__ __forceinline__ v2f pk_add(v2f a, v2f b) {
    v2f d; asm("v_pk_add_f32 %0, %1, %2" : "=v"(d) : "v"(a), "v"(b)); return d;
}
__device__ __forceinline__ v2f pk_mul(v2f a, v2f b) {
    v2f d; asm("v_pk_mul_f32 %0, %1, %2" : "=v"(d) : "v"(a), "v"(b)); return d;
}

__device__ __forceinline__ int prefix_base(unsigned long long m, int base) {
    return __builtin_amdgcn_mbcnt_hi((unsigned)(m >> 32),
           __builtin_amdgcn_mbcnt_lo((unsigned)m, (unsigned)base));
}

__global__ __launch_bounds__(256) void mo3e_kernel(const float* __restrict__ pos,
                                                   float* __restrict__ out) {
    __shared__ float sq[3072];            // flat xyz, 12 KB
    __shared__ int   slotrow[4][2][128];  // 4 KB: per wave x per target

    const int blk = blockIdx.x;
    const int b   = blk >> 5;             // 32 blocks per batch
    const int tid = threadIdx.x;
    const int w   = tid >> 6;
    const int l   = tid & 63;
    // first of this wave's 2 targets (even, wave-uniform scalar)
    const int i0  = __builtin_amdgcn_readfirstlane(((blk & 31) << 3) | (w << 1));

    // Stage batch positions: 3 coalesced float4 per thread.
    {
        const float4* g4 = (const float4*)(pos + (size_t)b * 3072);
        float4* s4 = (float4*)sq;
        s4[tid      ] = g4[tid      ];
        s4[tid + 256] = g4[tid + 256];
        s4[tid + 512] = g4[tid + 512];
    }
    __syncthreads();

    const float x0 = sq[3 * i0],     y0 = sq[3 * i0 + 1], z0 = sq[3 * i0 + 2];
    const float x1 = sq[3 * i0 + 3], y1 = sq[3 * i0 + 4], z1 = sq[3 * i0 + 5];
    // (q + (-t)) == (q - t); (q-t)^2 == (t-q)^2 bitwise. Per-half op order
    // (dx^2+dy^2)+dz^2 matches the reference; asm pk ops cannot be
    // contracted. Predicate d2 < 36.0f is bit-identical to sqrt(d2) < 6.
    const v2f nx[2] = {{-x0, -x0}, {-x1, -x1}};
    const v2f ny[2] = {{-y0, -y0}, {-y1, -y1}};
    const v2f nz[2] = {{-z0, -z0}, {-z1, -z1}};

    int* const rows[2] = { slotrow[w][0], slotrow[w][1] };
    const int dump = 64 + l;              // per-lane dead entry
    const int gs   = i0 >> 6;             // ii group holding both selves
    const int sl   = i0 & 63;             // self lane of target 0 (T=1 -> sl+1)

    unsigned long long m0ii[2], m0io[2];  // group-0 / group-4 masks for pads
    int cii[2] = {0, 0};
    int cio[2] = {KK, KK};                // io biased +32: slots land [32,64)

    // ---- main scan: 8 iters x 2 cands/lane, both targets share the reads ----
    int av = 3 * l;                       // dword index of cand (it*128 + l)
#pragma unroll
    for (int it = 0; it < 8; ++it) {
        const float xa = sq[av], ya = sq[av + 1], za = sq[av + 2];
        const float xb = sq[av + 192], yb = sq[av + 193], zb = sq[av + 194];
        av += 384;
        const v2f qx = {xa, xb}, qy = {ya, yb}, qz = {za, zb};
#pragma unroll
        for (int h = 0; h < 2; ++h) {
            const int g = 2 * it + h;               // 64-cand group
            const int idxv = (g << 6) | l;          // candidate index (shared)
#pragma unroll
            for (int T = 0; T < 2; ++T) {
                const v2f dx = pk_add(qx, nx[T]), dy = pk_add(qy, ny[T]),
                          dz = pk_add(qz, nz[T]);
                const v2f d2 = pk_add(pk_add(pk_mul(dx, dx), pk_mul(dy, dy)),
                                      pk_mul(dz, dz));
                const float dh = h ? d2.y : d2.x;
                bool pred = dh < 36.0f;
                unsigned long long ms = __ballot(pred);
                if (g == gs) {                      // wave-uniform, 1 of 16
                    ms &= ~(1ull << (sl + T));
                    pred = pred && (l != (sl + T));
                }
                if (g < 4) {                        // ii section
                    const int e = prefix_base(ms, cii[T]);
                    const bool wr = pred && (e < KK);
                    rows[T][wr ? e : dump] = idxv;
                    cii[T] += (int)__popcll(ms);
                    if (g == 0) m0ii[T] = ms;
                } else {                            // io section (biased)
                    const int e = prefix_base(ms, cio[T]);
                    const bool wr = pred && (e < 2 * KK);
                    rows[T][wr ? e : dump] = idxv;
                    cio[T] += (int)__popcll(ms);
                    if (g == 4) m0io[T] = ms;
                }
            }
        }
    }

    // ---- pads: single group each (sufficient whenever S0 < K) ----
#pragma unroll
    for (int T = 0; T < 2; ++T) {
        if (cii[T] < KK) {    // smallest ii invalids all in group 0
            const unsigned long long inv = ~m0ii[T];
            const int e = prefix_base(inv, cii[T]);
            const bool wr = ((inv >> l) & 1ull) && (e < KK);
            rows[T][wr ? e : dump] = l;             // cand = 0*64 + l
        }
        if (cio[T] < 2 * KK) {  // smallest io invalids all in group 4
            const unsigned long long inv = ~m0io[T];
            const int e = prefix_base(inv, cio[T]);
            const bool wr = ((inv >> l) & 1ull) && (e < 2 * KK);
            rows[T][wr ? e : dump] = 256 + l;       // cand = 4*64 + l
        }
    }

    // ---- epilogue: per target, 4 coalesced wave-wide stores ----
    const int goff = b << 10;
    float* const oSrc = out;
    float* const oTgt = out + EE;
    float* const oMsk = out + 2u * EE;
    float* const oDst = out + 3u * EE;
#pragma unroll
    for (int T = 0; T < 2; ++T) {
        const int idx = rows[T][l];       // same-wave RAW: lgkmcnt handles it
        const float qx = sq[3 * idx], qy = sq[3 * idx + 1], qz = sq[3 * idx + 2];
        const float xi = T ? x1 : x0, yi = T ? y1 : y0, zi = T ? z1 : z0;
        const float ddx = xi - qx, ddy = yi - qy, ddz = zi - qz;
        const float d2e = ddx * ddx + ddy * ddy + ddz * ddz;  // dist tol loose

        const bool isA = l < KK;          // lanes 0..31 = ii row, 32..63 = io
        const int  Sa  = cii[T] < KK ? cii[T] : KK;
        const int  Sb  = (cio[T] < 2 * KK ? cio[T] : 2 * KK) - KK;
        const bool mv  = (l & 31) < (isA ? Sa : Sb);
        const float dist = mv ? __builtin_amdgcn_sqrtf(d2e) : 0.0f;

        // 32-bit element offset; uniform array bases -> saddr-form stores.
        const unsigned e0  = (unsigned)((b << 8) + i0 + T) << 5;
        const unsigned off = (isA ? 0u : 4u * EE - 32u) + e0 + (unsigned)l;

        oSrc[off] = (float)(goff + idx);      // src (io idx already >= 256)
        oTgt[off] = (float)(goff + i0 + T);   // tgt
        oMsk[off] = mv ? 1.0f : 0.0f;         // mask
        oDst[off] = dist;                     // dist
    }
}

extern "C" void kernel_launch(void* const* d_in, const int* in_sizes, int n_in,
                              void* d_out, int out_size, void* d_ws, size_t ws_size,
                              hipStream_t stream) {
    const float* pos = (const float*)d_in[0];
    float* out = (float*)d_out;

    // 32 blocks/batch x 256 batches; 256 threads = 4 waves x 2 targets.
    mo3e_kernel<<<dim3(8192), dim3(256), 0, stream>>>(pos, out);
}